// Round 13
// baseline (273.456 us; speedup 1.0000x reference)
//
#include <hip/hip_runtime.h>

#define NEG_SLOPE 0.2f

typedef __attribute__((ext_vector_type(8))) short bf16x8;
typedef __attribute__((ext_vector_type(4))) float f32x4;
typedef __attribute__((ext_vector_type(2))) float f32x2;

__device__ __forceinline__ unsigned short f2bf(float f) {
  unsigned u = __builtin_bit_cast(unsigned, f);
  unsigned r = u + 0x7FFFu + ((u >> 16) & 1u);   // round-to-nearest-even
  return (unsigned short)(r >> 16);
}

// CSR slot: 32 B = {float ea[4]; int src; pad[3]} — fully written (nt, no RMW)

// ---------------- fused preprocessing ----------------

// blocks < eb: per-edge degree atomics. blocks eb..eb+63: W16t transpose.
// block eb+64: M[2][4][8] and vab[2][4][8].
__global__ void k_deg(const int* __restrict__ tgt, int* __restrict__ deg, int E, int eb,
                      const float* __restrict__ We1, const float* __restrict__ ae1,
                      const float* __restrict__ We2, const float* __restrict__ ae2,
                      const float* __restrict__ W2, const float* __restrict__ W1,
                      const float* __restrict__ as1, const float* __restrict__ ad1,
                      unsigned short* __restrict__ W16t,
                      float* __restrict__ M, float* __restrict__ vab) {
  int bid = blockIdx.x, tid = threadIdx.x;
  if (bid < eb) {
    int e = bid * 256 + tid;
    if (e < E) atomicAdd(&deg[tgt[e]], 1);
    return;
  }
  int mb = bid - eb;
  if (mb < 64) {
    int i = mb * 256 + tid;
    int c = i >> 7, k = i & 127;
    W16t[c * 128 + k] = f2bf(W2[k * 128 + c]);
    return;
  }
  if (tid < 64) {
    int layer = tid >> 5, kh = tid & 31;
    int k = kh >> 3, h = kh & 7;
    const float* We = layer ? We2 : We1;
    const float* ae = layer ? ae2 : ae1;
    float acc = 0.f;
    for (int c = 0; c < 16; ++c) acc += We[k * 128 + h * 16 + c] * ae[h * 16 + c];
    M[layer * 32 + k * 8 + h] = acc;
  } else if (tid < 128) {
    int i = tid - 64;
    int kind = i >> 5, rem = i & 31;
    int d = rem >> 3, h = rem & 7;
    const float* att = kind ? ad1 : as1;
    float acc = 0.f;
    for (int c = 0; c < 16; ++c) acc += W1[d * 128 + h * 16 + c] * att[h * 16 + c];
    vab[kind * 32 + d * 8 + h] = acc;
  }
}

// blocks < nbB: per-block sums of deg over 256-element chunks.
// blocks >= nbB: layer-1 node terms (a_s/a_d via low-rank vab tables).
__global__ __launch_bounds__(256) void k_bsum(const int* __restrict__ deg,
                                              int* __restrict__ bsum, int n, int nbB,
                                              const float* __restrict__ x,
                                              const float* __restrict__ vab,
                                              float* __restrict__ a_s, float* __restrict__ a_d,
                                              int N) {
  int bid = blockIdx.x, tid = threadIdx.x;
  if (bid >= nbB) {
    int idx = (bid - nbB) * 256 + tid;
    int nn = idx >> 3, h = idx & 7;
    if (nn >= N) return;
    float4 xr = *reinterpret_cast<const float4*>(x + (size_t)nn * 4);
    a_s[idx] = xr.x * vab[h] + xr.y * vab[8 + h] + xr.z * vab[16 + h] + xr.w * vab[24 + h];
    a_d[idx] = xr.x * vab[32 + h] + xr.y * vab[40 + h] + xr.z * vab[48 + h] + xr.w * vab[56 + h];
    return;
  }
  __shared__ int ws[4];
  int i = bid * 256 + tid;
  int lane = tid & 63, wv = tid >> 6;
  int v = (i < n) ? deg[i] : 0;
  #pragma unroll
  for (int o = 1; o < 64; o <<= 1) v += __shfl_xor(v, o, 64);
  if (lane == 0) ws[wv] = v;
  __syncthreads();
  if (tid == 0) bsum[bid] = ws[0] + ws[1] + ws[2] + ws[3];
}

// fused scan: each block redundantly sums bsum[0..bid), then per-block scan -> off[i+1]
__global__ __launch_bounds__(256) void k_off(const int* __restrict__ deg,
                                             const int* __restrict__ bsum,
                                             int* __restrict__ off, int n, int nbB) {
  __shared__ int ws[4];
  __shared__ int pres[4];
  int bid = blockIdx.x, tid = threadIdx.x;
  int lane = tid & 63, wv = tid >> 6;
  int partial = 0;
  for (int i = tid; i < bid; i += 256) partial += bsum[i];
  #pragma unroll
  for (int o = 1; o < 64; o <<= 1) partial += __shfl_xor(partial, o, 64);
  if (lane == 0) pres[wv] = partial;
  __syncthreads();
  int pre0 = pres[0] + pres[1] + pres[2] + pres[3];
  int i = bid * 256 + tid;
  int v = (i < n) ? deg[i] : 0;
  int sc = v;
  #pragma unroll
  for (int o = 1; o < 64; o <<= 1) { int t = __shfl_up(sc, o, 64); if (lane >= o) sc += t; }
  if (lane == 63) ws[wv] = sc;
  __syncthreads();
  int pre = pre0;
  #pragma unroll
  for (int w = 0; w < 3; ++w) if (wv > w) pre += ws[w];
  int incl = pre + sc;
  if (i < n) off[i + 1] = incl;
  if (i == 0) off[0] = 0;
}

// scatter edges into CSR slots: two nontemporal 16B stores write the FULL 32B
// slot (no partial-line RMW, no L2 pollution).
__global__ void k_filledge(const int* __restrict__ src, const int* __restrict__ tgt,
                           const float* __restrict__ eattr,
                           const int* __restrict__ off, int* __restrict__ cur,
                           float* __restrict__ slot, int E) {
  int e = blockIdx.x * blockDim.x + threadIdx.x;
  if (e >= E) return;
  int t = tgt[e];
  int pos = off[t] + atomicAdd(&cur[t], 1);
  float4 eav4 = reinterpret_cast<const float4*>(eattr)[e];
  f32x4 eav = {eav4.x, eav4.y, eav4.z, eav4.w};
  f32x4 sv = {__builtin_bit_cast(float, src[e]), 0.f, 0.f, 0.f};
  __builtin_nontemporal_store(eav, reinterpret_cast<f32x4*>(slot) + (size_t)pos * 2);
  __builtin_nontemporal_store(sv, reinterpret_cast<f32x4*>(slot) + (size_t)pos * 2 + 1);
}

// ---------------- layer kernels ----------------

// layer-2 linear via MFMA: h2 = x16 @ W2 (bf16 in, f32 acc). One wave per 16-node tile.
__global__ __launch_bounds__(256) void k_node2(const unsigned short* __restrict__ x16,
    const unsigned short* __restrict__ W16t,
    const float* __restrict__ as_, const float* __restrict__ ad_,
    unsigned short* __restrict__ h16, float* __restrict__ a_s, float* __restrict__ a_d, int N) {
  int wv = threadIdx.x >> 6, lane = threadIdx.x & 63;
  int n0 = (blockIdx.x * 4 + wv) * 16;
  if (n0 >= N) return;
  int r = lane & 15, g = lane >> 4;
  bf16x8 a[4];
  #pragma unroll
  for (int kb = 0; kb < 4; ++kb)
    a[kb] = *reinterpret_cast<const bf16x8*>(x16 + (size_t)(n0 + r) * 128 + kb * 32 + g * 8);
  #pragma unroll
  for (int t = 0; t < 8; ++t) {
    f32x4 acc = {0.f, 0.f, 0.f, 0.f};
    #pragma unroll
    for (int kb = 0; kb < 4; ++kb) {
      bf16x8 b = *reinterpret_cast<const bf16x8*>(W16t + (size_t)(t * 16 + r) * 128 + kb * 32 + g * 8);
      acc = __builtin_amdgcn_mfma_f32_16x16x32_bf16(a[kb], b, acc, 0, 0, 0);
    }
    float asv = as_[t * 16 + r], adv = ad_[t * 16 + r];
    float ps[4], pd[4];
    #pragma unroll
    for (int j = 0; j < 4; ++j) { ps[j] = acc[j] * asv; pd[j] = acc[j] * adv; }
    #pragma unroll
    for (int o = 1; o < 16; o <<= 1) {
      #pragma unroll
      for (int j = 0; j < 4; ++j) {
        ps[j] += __shfl_xor(ps[j], o, 64);
        pd[j] += __shfl_xor(pd[j], o, 64);
      }
    }
    #pragma unroll
    for (int j = 0; j < 4; ++j) {
      int row = n0 + g * 4 + j;
      if (row < N) {
        h16[(size_t)row * 128 + t * 16 + r] = f2bf(acc[j]);
        if (r == 0) { a_s[(size_t)row * 8 + t] = ps[j]; a_d[(size_t)row * 8 + t] = pd[j]; }
      }
    }
  }
}

// layer-1 aggregate via LINEARITY with analytic self-loop term.
__global__ __launch_bounds__(256) void k_aggr1(const float* __restrict__ slot,
    const int* __restrict__ off, const float* __restrict__ a_s, const float* __restrict__ a_d,
    const float* __restrict__ M, const float* __restrict__ x,
    const float* __restrict__ W, const float* __restrict__ bias,
    unsigned short* __restrict__ x16, int N) {
  int wid = (blockIdx.x * blockDim.x + threadIdx.x) >> 6;
  if (wid >= N) return;
  int lane = threadIdx.x & 63;
  int j = lane >> 3, h = lane & 7;
  float M0 = M[h], M1 = M[8 + h], M2 = M[16 + h], M3 = M[24 + h];
  float adv = a_d[(size_t)wid * 8 + h];
  int beg = off[wid], end = off[wid + 1];
  int cnt = end - beg;
  float S = 0.f, X0 = 0.f, X1 = 0.f, X2 = 0.f, X3 = 0.f, Q = 0.f;
  for (int i = beg; i < end; i += 8) {
    int ii = i + j;
    bool act = ii < end;
    int ib = act ? ii : end - 1;
    float4 ea = *reinterpret_cast<const float4*>(slot + (size_t)ib * 8);
    int s = reinterpret_cast<const int*>(slot)[(size_t)ib * 8 + 4];
    float asv = a_s[(size_t)s * 8 + h];
    float4 xv = *reinterpret_cast<const float4*>(x + (size_t)s * 4);
    float qe = ea.x * M0 + ea.y * M1 + ea.z * M2 + ea.w * M3;
    float a = asv + adv + qe;
    a = a > 0.f ? a : NEG_SLOPE * a;
    float p = act ? __expf(a) : 0.f;
    Q += act ? qe : 0.f;
    S += p; X0 += p * xv.x; X1 += p * xv.y; X2 += p * xv.z; X3 += p * xv.w;
  }
  #pragma unroll
  for (int o = 8; o < 64; o <<= 1) {
    S  += __shfl_xor(S, o, 64);  Q  += __shfl_xor(Q, o, 64);
    X0 += __shfl_xor(X0, o, 64); X1 += __shfl_xor(X1, o, 64);
    X2 += __shfl_xor(X2, o, 64); X3 += __shfl_xor(X3, o, 64);
  }
  // analytic self-loop: ea_self = mean(ea) -> q_self = Q/cnt (own h class)
  {
    float qs = Q / (float)max(cnt, 1);
    float asS = a_s[(size_t)wid * 8 + h];
    float aS = asS + adv + qs;
    aS = aS > 0.f ? aS : NEG_SLOPE * aS;
    float pS = __expf(aS);
    float4 xw = *reinterpret_cast<const float4*>(x + (size_t)wid * 4);
    S += pS; X0 += pS * xw.x; X1 += pS * xw.y; X2 += pS * xw.z; X3 += pS * xw.w;
  }
  int H = lane >> 3;
  float Sh = __shfl(S, H, 64);
  float y0 = __shfl(X0, H, 64), y1 = __shfl(X1, H, 64);
  float y2 = __shfl(X2, H, 64), y3 = __shfl(X3, H, 64);
  float inv = 1.f / (Sh + 1e-16f);
  int c0 = lane * 2, c1 = lane * 2 + 1;
  float o0 = (y0 * W[c0] + y1 * W[128 + c0] + y2 * W[256 + c0] + y3 * W[384 + c0]) * inv + bias[c0];
  float o1 = (y0 * W[c1] + y1 * W[128 + c1] + y2 * W[256 + c1] + y3 * W[384 + c1]) * inv + bias[c1];
  o0 = fmaxf(o0, 0.f); o1 = fmaxf(o1, 0.f);
  unsigned pk = ((unsigned)f2bf(o1) << 16) | (unsigned)f2bf(o0);
  __builtin_nontemporal_store(pk, reinterpret_cast<unsigned*>(x16 + (size_t)wid * 128 + lane * 2));
}

// layer-2 aggregate (single node/wave) with analytic self-loop term.
__global__ __launch_bounds__(256) void k_aggr2(const float* __restrict__ slot,
    const int* __restrict__ off, const float* __restrict__ a_s, const float* __restrict__ a_d,
    const float* __restrict__ M, const unsigned short* __restrict__ h16,
    const float* __restrict__ bias, float* __restrict__ xout, int N) {
  int wid = (blockIdx.x * blockDim.x + threadIdx.x) >> 6;
  if (wid >= N) return;
  int lane = threadIdx.x & 63;
  int H = lane >> 3;                   // consumer head
  int ja = lane >> 3, ha = lane & 7;   // alpha role: edge ja, head ha
  float Ma0 = M[ha], Ma1 = M[8 + ha], Ma2 = M[16 + ha], Ma3 = M[24 + ha];
  float adA = a_d[(size_t)wid * 8 + ha];
  int beg = off[wid], end = off[wid + 1];
  int cnt = end - beg;
  float sum = 0.f, acc0 = 0.f, acc1 = 0.f, Q = 0.f;
  for (int i = beg; i < end; i += 8) {
    int ii = i + ja;
    bool act = ii < end;
    int ib = act ? ii : beg;
    float4 ea = *reinterpret_cast<const float4*>(slot + (size_t)ib * 8);
    int sA = reinterpret_cast<const int*>(slot)[(size_t)ib * 8 + 4];
    float asv = a_s[(size_t)sA * 8 + ha];
    float qe = ea.x * Ma0 + ea.y * Ma1 + ea.z * Ma2 + ea.w * Ma3;
    float a = asv + adA + qe;
    a = a > 0.f ? a : NEG_SLOPE * a;
    float p = act ? __expf(a) : 0.f;
    Q += act ? qe : 0.f;
    #pragma unroll
    for (int jj = 0; jj < 8; ++jj) {
      int sj = __shfl(sA, jj * 8, 64);
      float pj = __shfl(p, jj * 8 + H, 64);
      unsigned hu = *reinterpret_cast<const unsigned*>(h16 + (size_t)sj * 128 + lane * 2);
      sum += pj;
      acc0 += pj * __builtin_bit_cast(float, hu << 16);
      acc1 += pj * __builtin_bit_cast(float, hu & 0xFFFF0000u);
    }
  }
  #pragma unroll
  for (int o = 8; o < 64; o <<= 1) Q += __shfl_xor(Q, o, 64);
  {
    float qs = __shfl(Q, H, 64) / (float)max(cnt, 1);
    float aS = a_s[(size_t)wid * 8 + H] + a_d[(size_t)wid * 8 + H] + qs;
    aS = aS > 0.f ? aS : NEG_SLOPE * aS;
    float pS = __expf(aS);
    unsigned hu = *reinterpret_cast<const unsigned*>(h16 + (size_t)wid * 128 + lane * 2);
    sum += pS;
    acc0 += pS * __builtin_bit_cast(float, hu << 16);
    acc1 += pS * __builtin_bit_cast(float, hu & 0xFFFF0000u);
  }
  float inv = 1.f / (sum + 1e-16f);
  float o0 = fmaxf(acc0 * inv + bias[lane * 2], 0.f);
  float o1 = fmaxf(acc1 * inv + bias[lane * 2 + 1], 0.f);
  f32x2 ov = {o0, o1};
  __builtin_nontemporal_store(ov, reinterpret_cast<f32x2*>(xout + (size_t)wid * 128 + lane * 2));
}

// ---------------- pooling + FC ----------------

#define PROWS 128
__global__ __launch_bounds__(128) void k_pool(const float* __restrict__ x,
    const int* __restrict__ batch, float* __restrict__ pool, int* __restrict__ cntg, int N) {
  int c = threadIdx.x;
  int n0 = blockIdx.x * PROWS;
  if (n0 >= N) return;
  int nend = min(n0 + PROWS, N);
  float acc = 0.f; int cnt = 0; int g = batch[n0];
  for (int n = n0; n < nend; ++n) {
    int bn = batch[n];
    if (bn != g) {
      atomicAdd(&pool[(size_t)g * 128 + c], acc);
      if (c == 0) atomicAdd(&cntg[g], cnt);
      acc = 0.f; cnt = 0; g = bn;
    }
    acc += x[(size_t)n * 128 + c];
    cnt++;
  }
  atomicAdd(&pool[(size_t)g * 128 + c], acc);
  if (c == 0) atomicAdd(&cntg[g], cnt);
}

__global__ __launch_bounds__(128) void k_fc(const float* __restrict__ pool,
    const int* __restrict__ cntg, const float* __restrict__ fcw,
    const float* __restrict__ fcb, float* __restrict__ out, int G) {
  int g = blockIdx.x, c = threadIdx.x;
  __shared__ float r0[2], r1[2];
  float inv = 1.f / (float)max(cntg[g], 1);
  float v = pool[(size_t)g * 128 + c] * inv;
  float p0 = v * fcw[c * 2], p1 = v * fcw[c * 2 + 1];
  for (int o = 1; o < 64; o <<= 1) { p0 += __shfl_xor(p0, o, 64); p1 += __shfl_xor(p1, o, 64); }
  if ((c & 63) == 0) { r0[c >> 6] = p0; r1[c >> 6] = p1; }
  __syncthreads();
  if (c == 0) {
    out[g * 2]     = r0[0] + r0[1] + fcb[0];
    out[g * 2 + 1] = r1[0] + r1[1] + fcb[1];
  }
}

// ---------------- host ----------------

extern "C" void kernel_launch(void* const* d_in, const int* in_sizes, int n_in,
                              void* d_out, int out_size, void* d_ws, size_t ws_size,
                              hipStream_t stream) {
  const float* x     = (const float*)d_in[0];
  const int*   eidx  = (const int*)d_in[1];
  const int*   batch = (const int*)d_in[2];
  const float* eattr = (const float*)d_in[3];
  const float* W1  = (const float*)d_in[4];
  const float* as1 = (const float*)d_in[5];
  const float* ad1 = (const float*)d_in[6];
  const float* We1 = (const float*)d_in[7];
  const float* ae1 = (const float*)d_in[8];
  const float* b1  = (const float*)d_in[9];
  const float* W2  = (const float*)d_in[10];
  const float* as2 = (const float*)d_in[11];
  const float* ad2 = (const float*)d_in[12];
  const float* We2 = (const float*)d_in[13];
  const float* ae2 = (const float*)d_in[14];
  const float* b2  = (const float*)d_in[15];
  const float* fcw = (const float*)d_in[16];
  const float* fcb = (const float*)d_in[17];

  const int N  = in_sizes[2];
  const int E  = in_sizes[1] / 2;
  const int G  = out_size / 2;
  const int eb = (E + 255) / 256;
  const int nbB = (N + 255) / 256;
  const int n1b = (N * 8 + 255) / 256;
  const int* srcI = eidx;
  const int* tgtI = eidx + E;

  char* w = (char*)d_ws;
  auto alloc = [&](size_t bytes) -> void* {
    void* p = (void*)w;
    w += (bytes + 255) & ~(size_t)255;
    return p;
  };
  int*   deg    = (int*)alloc((size_t)N * 8);        // deg + cur contiguous
  int*   cur    = deg + N;
  int*   bsum   = (int*)alloc((size_t)nbB * 4);
  int*   off    = (int*)alloc((size_t)(N + 1) * 4);
  float* slot   = (float*)alloc((size_t)E * 32);
  float* a_s    = (float*)alloc((size_t)N * 32);
  float* a_d    = (float*)alloc((size_t)N * 32);
  unsigned short* x16 = (unsigned short*)alloc((size_t)N * 256);
  unsigned short* h16 = (unsigned short*)alloc((size_t)N * 256);
  unsigned short* W16t = (unsigned short*)alloc(128 * 128 * 2);
  float* xbuf   = (float*)alloc((size_t)N * 512);
  float* M      = (float*)alloc(512);                // M[64] + vab[64]
  float* vab    = M + 64;
  float* pool   = (float*)alloc((size_t)G * 512 + (size_t)G * 4);
  int*   cntg   = (int*)(pool + (size_t)G * 128);

  hipMemsetAsync(deg, 0, (size_t)N * 8, stream);
  hipMemsetAsync(pool, 0, (size_t)G * 516, stream);

  k_deg<<<eb + 65, 256, 0, stream>>>(tgtI, deg, E, eb,
                                     We1, ae1, We2, ae2, W2, W1, as1, ad1, W16t, M, vab);
  k_bsum<<<nbB + n1b, 256, 0, stream>>>(deg, bsum, N, nbB, x, vab, a_s, a_d, N);
  k_off<<<nbB, 256, 0, stream>>>(deg, bsum, off, N, nbB);
  k_filledge<<<eb, 256, 0, stream>>>(srcI, tgtI, eattr, off, cur, slot, E);

  // layer 1 (linearity + analytic self-loop); output packed bf16
  k_aggr1<<<(N + 3) / 4, 256, 0, stream>>>(slot, off, a_s, a_d, M, x, W1, b1, x16, N);

  // layer 2 (MFMA linear + gather aggregate with analytic self-loop)
  k_node2<<<(N + 63) / 64, 256, 0, stream>>>(x16, W16t, as2, ad2, h16, a_s, a_d, N);
  k_aggr2<<<(N + 3) / 4, 256, 0, stream>>>(slot, off, a_s, a_d, M + 32, h16, b2, xbuf, N);

  // pool + fc
  k_pool<<<(N + PROWS - 1) / PROWS, 128, 0, stream>>>(xbuf, batch, pool, cntg, N);
  k_fc<<<G, 128, 0, stream>>>(pool, cntg, fcw, fcb, (float*)d_out, G);
}

// Round 14
// 207.056 us; speedup vs baseline: 1.3207x; 1.3207x over previous
//
#include <hip/hip_runtime.h>

#define NEG_SLOPE 0.2f

typedef __attribute__((ext_vector_type(8))) short bf16x8;
typedef __attribute__((ext_vector_type(4))) float f32x4;

__device__ __forceinline__ unsigned short f2bf(float f) {
  unsigned u = __builtin_bit_cast(unsigned, f);
  unsigned r = u + 0x7FFFu + ((u >> 16) & 1u);   // round-to-nearest-even
  return (unsigned short)(r >> 16);
}

// CSR slot: 32 B = {float ea[4]; int src; pad[3]} (plain stores; L2 merges halves)

// ---------------- fused preprocessing ----------------

// blocks < eb: per-edge degree atomics + slot-ordinal precompute.
// blocks eb..eb+63: W16t transpose. block eb+64: M and vab tables.
__global__ void k_deg(const int* __restrict__ tgt, int* __restrict__ deg,
                      int* __restrict__ ord, int E, int eb,
                      const float* __restrict__ We1, const float* __restrict__ ae1,
                      const float* __restrict__ We2, const float* __restrict__ ae2,
                      const float* __restrict__ W2, const float* __restrict__ W1,
                      const float* __restrict__ as1, const float* __restrict__ ad1,
                      unsigned short* __restrict__ W16t,
                      float* __restrict__ M, float* __restrict__ vab) {
  int bid = blockIdx.x, tid = threadIdx.x;
  if (bid < eb) {
    int e = bid * 256 + tid;
    if (e < E) ord[e] = atomicAdd(&deg[tgt[e]], 1);
    return;
  }
  int mb = bid - eb;
  if (mb < 64) {
    int i = mb * 256 + tid;
    int c = i >> 7, k = i & 127;
    W16t[c * 128 + k] = f2bf(W2[k * 128 + c]);
    return;
  }
  if (tid < 64) {
    int layer = tid >> 5, kh = tid & 31;
    int k = kh >> 3, h = kh & 7;
    const float* We = layer ? We2 : We1;
    const float* ae = layer ? ae2 : ae1;
    float acc = 0.f;
    for (int c = 0; c < 16; ++c) acc += We[k * 128 + h * 16 + c] * ae[h * 16 + c];
    M[layer * 32 + k * 8 + h] = acc;
  } else if (tid < 128) {
    int i = tid - 64;
    int kind = i >> 5, rem = i & 31;
    int d = rem >> 3, h = rem & 7;
    const float* att = kind ? ad1 : as1;
    float acc = 0.f;
    for (int c = 0; c < 16; ++c) acc += W1[d * 128 + h * 16 + c] * att[h * 16 + c];
    vab[kind * 32 + d * 8 + h] = acc;
  }
}

// blocks < nbB: per-block sums of deg over 256-element chunks.
// blocks >= nbB: layer-1 node terms (a_s/a_d via low-rank vab tables).
__global__ __launch_bounds__(256) void k_bsum(const int* __restrict__ deg,
                                              int* __restrict__ bsum, int n, int nbB,
                                              const float* __restrict__ x,
                                              const float* __restrict__ vab,
                                              float* __restrict__ a_s, float* __restrict__ a_d,
                                              int N) {
  int bid = blockIdx.x, tid = threadIdx.x;
  if (bid >= nbB) {
    int idx = (bid - nbB) * 256 + tid;
    int nn = idx >> 3, h = idx & 7;
    if (nn >= N) return;
    float4 xr = *reinterpret_cast<const float4*>(x + (size_t)nn * 4);
    a_s[idx] = xr.x * vab[h] + xr.y * vab[8 + h] + xr.z * vab[16 + h] + xr.w * vab[24 + h];
    a_d[idx] = xr.x * vab[32 + h] + xr.y * vab[40 + h] + xr.z * vab[48 + h] + xr.w * vab[56 + h];
    return;
  }
  __shared__ int ws[4];
  int i = bid * 256 + tid;
  int lane = tid & 63, wv = tid >> 6;
  int v = (i < n) ? deg[i] : 0;
  #pragma unroll
  for (int o = 1; o < 64; o <<= 1) v += __shfl_xor(v, o, 64);
  if (lane == 0) ws[wv] = v;
  __syncthreads();
  if (tid == 0) bsum[bid] = ws[0] + ws[1] + ws[2] + ws[3];
}

// fused scan: each block redundantly sums bsum[0..bid), then per-block scan -> off[i+1]
__global__ __launch_bounds__(256) void k_off(const int* __restrict__ deg,
                                             const int* __restrict__ bsum,
                                             int* __restrict__ off, int n, int nbB) {
  __shared__ int ws[4];
  __shared__ int pres[4];
  int bid = blockIdx.x, tid = threadIdx.x;
  int lane = tid & 63, wv = tid >> 6;
  int partial = 0;
  for (int i = tid; i < bid; i += 256) partial += bsum[i];
  #pragma unroll
  for (int o = 1; o < 64; o <<= 1) partial += __shfl_xor(partial, o, 64);
  if (lane == 0) pres[wv] = partial;
  __syncthreads();
  int pre0 = pres[0] + pres[1] + pres[2] + pres[3];
  int i = bid * 256 + tid;
  int v = (i < n) ? deg[i] : 0;
  int sc = v;
  #pragma unroll
  for (int o = 1; o < 64; o <<= 1) { int t = __shfl_up(sc, o, 64); if (lane >= o) sc += t; }
  if (lane == 63) ws[wv] = sc;
  __syncthreads();
  int pre = pre0;
  #pragma unroll
  for (int w = 0; w < 3; ++w) if (wv > w) pre += ws[w];
  int incl = pre + sc;
  if (i < n) off[i + 1] = incl;
  if (i == 0) off[0] = 0;
}

// scatter edges into CSR slots: no atomics (pos = off[t] + ord[e]); one 32B slot
// written with two plain 16B stores (L2 merges them into one line write).
__global__ void k_filledge(const int* __restrict__ src, const int* __restrict__ tgt,
                           const float* __restrict__ eattr, const int* __restrict__ ord,
                           const int* __restrict__ off, float* __restrict__ slot, int E) {
  int e = blockIdx.x * blockDim.x + threadIdx.x;
  if (e >= E) return;
  float4 eav = reinterpret_cast<const float4*>(eattr)[e];
  int sv = src[e];
  int pos = off[tgt[e]] + ord[e];
  reinterpret_cast<float4*>(slot)[(size_t)pos * 2] = eav;
  reinterpret_cast<int*>(slot)[(size_t)pos * 8 + 4] = sv;
}

// ---------------- layer kernels ----------------

// layer-2 linear via MFMA: h2 = x16 @ W2 (bf16 in, f32 acc). One wave per 16-node tile.
__global__ __launch_bounds__(256) void k_node2(const unsigned short* __restrict__ x16,
    const unsigned short* __restrict__ W16t,
    const float* __restrict__ as_, const float* __restrict__ ad_,
    unsigned short* __restrict__ h16, float* __restrict__ a_s, float* __restrict__ a_d, int N) {
  int wv = threadIdx.x >> 6, lane = threadIdx.x & 63;
  int n0 = (blockIdx.x * 4 + wv) * 16;
  if (n0 >= N) return;
  int r = lane & 15, g = lane >> 4;
  bf16x8 a[4];
  #pragma unroll
  for (int kb = 0; kb < 4; ++kb)
    a[kb] = *reinterpret_cast<const bf16x8*>(x16 + (size_t)(n0 + r) * 128 + kb * 32 + g * 8);
  #pragma unroll
  for (int t = 0; t < 8; ++t) {
    f32x4 acc = {0.f, 0.f, 0.f, 0.f};
    #pragma unroll
    for (int kb = 0; kb < 4; ++kb) {
      bf16x8 b = *reinterpret_cast<const bf16x8*>(W16t + (size_t)(t * 16 + r) * 128 + kb * 32 + g * 8);
      acc = __builtin_amdgcn_mfma_f32_16x16x32_bf16(a[kb], b, acc, 0, 0, 0);
    }
    float asv = as_[t * 16 + r], adv = ad_[t * 16 + r];
    float ps[4], pd[4];
    #pragma unroll
    for (int j = 0; j < 4; ++j) { ps[j] = acc[j] * asv; pd[j] = acc[j] * adv; }
    #pragma unroll
    for (int o = 1; o < 16; o <<= 1) {
      #pragma unroll
      for (int j = 0; j < 4; ++j) {
        ps[j] += __shfl_xor(ps[j], o, 64);
        pd[j] += __shfl_xor(pd[j], o, 64);
      }
    }
    #pragma unroll
    for (int j = 0; j < 4; ++j) {
      int row = n0 + g * 4 + j;
      if (row < N) {
        h16[(size_t)row * 128 + t * 16 + r] = f2bf(acc[j]);
        if (r == 0) { a_s[(size_t)row * 8 + t] = ps[j]; a_d[(size_t)row * 8 + t] = pd[j]; }
      }
    }
  }
}

// layer-1 aggregate via LINEARITY with analytic self-loop term.
__global__ __launch_bounds__(256) void k_aggr1(const float* __restrict__ slot,
    const int* __restrict__ off, const float* __restrict__ a_s, const float* __restrict__ a_d,
    const float* __restrict__ M, const float* __restrict__ x,
    const float* __restrict__ W, const float* __restrict__ bias,
    unsigned short* __restrict__ x16, int N) {
  int wid = (blockIdx.x * blockDim.x + threadIdx.x) >> 6;
  if (wid >= N) return;
  int lane = threadIdx.x & 63;
  int j = lane >> 3, h = lane & 7;
  float M0 = M[h], M1 = M[8 + h], M2 = M[16 + h], M3 = M[24 + h];
  float adv = a_d[(size_t)wid * 8 + h];
  int beg = off[wid], end = off[wid + 1];
  int cnt = end - beg;
  float S = 0.f, X0 = 0.f, X1 = 0.f, X2 = 0.f, X3 = 0.f, Q = 0.f;
  for (int i = beg; i < end; i += 8) {
    int ii = i + j;
    bool act = ii < end;
    int ib = act ? ii : end - 1;
    float4 ea = *reinterpret_cast<const float4*>(slot + (size_t)ib * 8);
    int s = reinterpret_cast<const int*>(slot)[(size_t)ib * 8 + 4];
    float asv = a_s[(size_t)s * 8 + h];
    float4 xv = *reinterpret_cast<const float4*>(x + (size_t)s * 4);
    float qe = ea.x * M0 + ea.y * M1 + ea.z * M2 + ea.w * M3;
    float a = asv + adv + qe;
    a = a > 0.f ? a : NEG_SLOPE * a;
    float p = act ? __expf(a) : 0.f;
    Q += act ? qe : 0.f;
    S += p; X0 += p * xv.x; X1 += p * xv.y; X2 += p * xv.z; X3 += p * xv.w;
  }
  #pragma unroll
  for (int o = 8; o < 64; o <<= 1) {
    S  += __shfl_xor(S, o, 64);  Q  += __shfl_xor(Q, o, 64);
    X0 += __shfl_xor(X0, o, 64); X1 += __shfl_xor(X1, o, 64);
    X2 += __shfl_xor(X2, o, 64); X3 += __shfl_xor(X3, o, 64);
  }
  // analytic self-loop: ea_self = mean(ea) -> q_self = Q/cnt (own h class)
  {
    float qs = Q / (float)max(cnt, 1);
    float asS = a_s[(size_t)wid * 8 + h];
    float aS = asS + adv + qs;
    aS = aS > 0.f ? aS : NEG_SLOPE * aS;
    float pS = __expf(aS);
    float4 xw = *reinterpret_cast<const float4*>(x + (size_t)wid * 4);
    S += pS; X0 += pS * xw.x; X1 += pS * xw.y; X2 += pS * xw.z; X3 += pS * xw.w;
  }
  int H = lane >> 3;
  float Sh = __shfl(S, H, 64);
  float y0 = __shfl(X0, H, 64), y1 = __shfl(X1, H, 64);
  float y2 = __shfl(X2, H, 64), y3 = __shfl(X3, H, 64);
  float inv = 1.f / (Sh + 1e-16f);
  int c0 = lane * 2, c1 = lane * 2 + 1;
  float o0 = (y0 * W[c0] + y1 * W[128 + c0] + y2 * W[256 + c0] + y3 * W[384 + c0]) * inv + bias[c0];
  float o1 = (y0 * W[c1] + y1 * W[128 + c1] + y2 * W[256 + c1] + y3 * W[384 + c1]) * inv + bias[c1];
  o0 = fmaxf(o0, 0.f); o1 = fmaxf(o1, 0.f);
  unsigned pk = ((unsigned)f2bf(o1) << 16) | (unsigned)f2bf(o0);
  *reinterpret_cast<unsigned*>(x16 + (size_t)wid * 128 + lane * 2) = pk;
}

// layer-2 aggregate (single node/wave) with analytic self-loop term.
__global__ __launch_bounds__(256) void k_aggr2(const float* __restrict__ slot,
    const int* __restrict__ off, const float* __restrict__ a_s, const float* __restrict__ a_d,
    const float* __restrict__ M, const unsigned short* __restrict__ h16,
    const float* __restrict__ bias, float* __restrict__ xout, int N) {
  int wid = (blockIdx.x * blockDim.x + threadIdx.x) >> 6;
  if (wid >= N) return;
  int lane = threadIdx.x & 63;
  int H = lane >> 3;                   // consumer head
  int ja = lane >> 3, ha = lane & 7;   // alpha role: edge ja, head ha
  float Ma0 = M[ha], Ma1 = M[8 + ha], Ma2 = M[16 + ha], Ma3 = M[24 + ha];
  float adA = a_d[(size_t)wid * 8 + ha];
  int beg = off[wid], end = off[wid + 1];
  int cnt = end - beg;
  float sum = 0.f, acc0 = 0.f, acc1 = 0.f, Q = 0.f;
  for (int i = beg; i < end; i += 8) {
    int ii = i + ja;
    bool act = ii < end;
    int ib = act ? ii : beg;
    float4 ea = *reinterpret_cast<const float4*>(slot + (size_t)ib * 8);
    int sA = reinterpret_cast<const int*>(slot)[(size_t)ib * 8 + 4];
    float asv = a_s[(size_t)sA * 8 + ha];
    float qe = ea.x * Ma0 + ea.y * Ma1 + ea.z * Ma2 + ea.w * Ma3;
    float a = asv + adA + qe;
    a = a > 0.f ? a : NEG_SLOPE * a;
    float p = act ? __expf(a) : 0.f;
    Q += act ? qe : 0.f;
    #pragma unroll
    for (int jj = 0; jj < 8; ++jj) {
      int sj = __shfl(sA, jj * 8, 64);
      float pj = __shfl(p, jj * 8 + H, 64);
      unsigned hu = *reinterpret_cast<const unsigned*>(h16 + (size_t)sj * 128 + lane * 2);
      sum += pj;
      acc0 += pj * __builtin_bit_cast(float, hu << 16);
      acc1 += pj * __builtin_bit_cast(float, hu & 0xFFFF0000u);
    }
  }
  #pragma unroll
  for (int o = 8; o < 64; o <<= 1) Q += __shfl_xor(Q, o, 64);
  {
    float qs = __shfl(Q, H, 64) / (float)max(cnt, 1);
    float aS = a_s[(size_t)wid * 8 + H] + a_d[(size_t)wid * 8 + H] + qs;
    aS = aS > 0.f ? aS : NEG_SLOPE * aS;
    float pS = __expf(aS);
    unsigned hu = *reinterpret_cast<const unsigned*>(h16 + (size_t)wid * 128 + lane * 2);
    sum += pS;
    acc0 += pS * __builtin_bit_cast(float, hu << 16);
    acc1 += pS * __builtin_bit_cast(float, hu & 0xFFFF0000u);
  }
  float inv = 1.f / (sum + 1e-16f);
  float o0 = fmaxf(acc0 * inv + bias[lane * 2], 0.f);
  float o1 = fmaxf(acc1 * inv + bias[lane * 2 + 1], 0.f);
  *reinterpret_cast<float2*>(xout + (size_t)wid * 128 + lane * 2) = make_float2(o0, o1);
}

// ---------------- pooling + FC ----------------

#define PROWS 128
__global__ __launch_bounds__(128) void k_pool(const float* __restrict__ x,
    const int* __restrict__ batch, float* __restrict__ pool, int* __restrict__ cntg, int N) {
  int c = threadIdx.x;
  int n0 = blockIdx.x * PROWS;
  if (n0 >= N) return;
  int nend = min(n0 + PROWS, N);
  float acc = 0.f; int cnt = 0; int g = batch[n0];
  for (int n = n0; n < nend; ++n) {
    int bn = batch[n];
    if (bn != g) {
      atomicAdd(&pool[(size_t)g * 128 + c], acc);
      if (c == 0) atomicAdd(&cntg[g], cnt);
      acc = 0.f; cnt = 0; g = bn;
    }
    acc += x[(size_t)n * 128 + c];
    cnt++;
  }
  atomicAdd(&pool[(size_t)g * 128 + c], acc);
  if (c == 0) atomicAdd(&cntg[g], cnt);
}

__global__ __launch_bounds__(128) void k_fc(const float* __restrict__ pool,
    const int* __restrict__ cntg, const float* __restrict__ fcw,
    const float* __restrict__ fcb, float* __restrict__ out, int G) {
  int g = blockIdx.x, c = threadIdx.x;
  __shared__ float r0[2], r1[2];
  float inv = 1.f / (float)max(cntg[g], 1);
  float v = pool[(size_t)g * 128 + c] * inv;
  float p0 = v * fcw[c * 2], p1 = v * fcw[c * 2 + 1];
  for (int o = 1; o < 64; o <<= 1) { p0 += __shfl_xor(p0, o, 64); p1 += __shfl_xor(p1, o, 64); }
  if ((c & 63) == 0) { r0[c >> 6] = p0; r1[c >> 6] = p1; }
  __syncthreads();
  if (c == 0) {
    out[g * 2]     = r0[0] + r0[1] + fcb[0];
    out[g * 2 + 1] = r1[0] + r1[1] + fcb[1];
  }
}

// ---------------- host ----------------

extern "C" void kernel_launch(void* const* d_in, const int* in_sizes, int n_in,
                              void* d_out, int out_size, void* d_ws, size_t ws_size,
                              hipStream_t stream) {
  const float* x     = (const float*)d_in[0];
  const int*   eidx  = (const int*)d_in[1];
  const int*   batch = (const int*)d_in[2];
  const float* eattr = (const float*)d_in[3];
  const float* W1  = (const float*)d_in[4];
  const float* as1 = (const float*)d_in[5];
  const float* ad1 = (const float*)d_in[6];
  const float* We1 = (const float*)d_in[7];
  const float* ae1 = (const float*)d_in[8];
  const float* b1  = (const float*)d_in[9];
  const float* W2  = (const float*)d_in[10];
  const float* as2 = (const float*)d_in[11];
  const float* ad2 = (const float*)d_in[12];
  const float* We2 = (const float*)d_in[13];
  const float* ae2 = (const float*)d_in[14];
  const float* b2  = (const float*)d_in[15];
  const float* fcw = (const float*)d_in[16];
  const float* fcb = (const float*)d_in[17];

  const int N  = in_sizes[2];
  const int E  = in_sizes[1] / 2;
  const int G  = out_size / 2;
  const int eb = (E + 255) / 256;
  const int nbB = (N + 255) / 256;
  const int n1b = (N * 8 + 255) / 256;
  const int* srcI = eidx;
  const int* tgtI = eidx + E;

  char* w = (char*)d_ws;
  auto alloc = [&](size_t bytes) -> void* {
    void* p = (void*)w;
    w += (bytes + 255) & ~(size_t)255;
    return p;
  };
  int*   deg    = (int*)alloc((size_t)N * 4);
  int*   ord    = (int*)alloc((size_t)E * 4);
  int*   bsum   = (int*)alloc((size_t)nbB * 4);
  int*   off    = (int*)alloc((size_t)(N + 1) * 4);
  float* slot   = (float*)alloc((size_t)E * 32);
  float* a_s    = (float*)alloc((size_t)N * 32);
  float* a_d    = (float*)alloc((size_t)N * 32);
  unsigned short* x16 = (unsigned short*)alloc((size_t)N * 256);
  unsigned short* h16 = (unsigned short*)alloc((size_t)N * 256);
  unsigned short* W16t = (unsigned short*)alloc(128 * 128 * 2);
  float* xbuf   = (float*)alloc((size_t)N * 512);
  float* M      = (float*)alloc(512);                // M[64] + vab[64]
  float* vab    = M + 64;
  float* pool   = (float*)alloc((size_t)G * 512 + (size_t)G * 4);
  int*   cntg   = (int*)(pool + (size_t)G * 128);

  hipMemsetAsync(deg, 0, (size_t)N * 4, stream);
  hipMemsetAsync(pool, 0, (size_t)G * 516, stream);

  k_deg<<<eb + 65, 256, 0, stream>>>(tgtI, deg, ord, E, eb,
                                     We1, ae1, We2, ae2, W2, W1, as1, ad1, W16t, M, vab);
  k_bsum<<<nbB + n1b, 256, 0, stream>>>(deg, bsum, N, nbB, x, vab, a_s, a_d, N);
  k_off<<<nbB, 256, 0, stream>>>(deg, bsum, off, N, nbB);
  k_filledge<<<eb, 256, 0, stream>>>(srcI, tgtI, eattr, ord, off, slot, E);

  // layer 1 (linearity + analytic self-loop); output packed bf16
  k_aggr1<<<(N + 3) / 4, 256, 0, stream>>>(slot, off, a_s, a_d, M, x, W1, b1, x16, N);

  // layer 2 (MFMA linear + gather aggregate with analytic self-loop)
  k_node2<<<(N + 63) / 64, 256, 0, stream>>>(x16, W16t, as2, ad2, h16, a_s, a_d, N);
  k_aggr2<<<(N + 3) / 4, 256, 0, stream>>>(slot, off, a_s, a_d, M + 32, h16, b2, xbuf, N);

  // pool + fc
  k_pool<<<(N + PROWS - 1) / PROWS, 128, 0, stream>>>(xbuf, batch, pool, cntg, N);
  k_fc<<<G, 128, 0, stream>>>(pool, cntg, fcw, fcb, (float*)d_out, G);
}

// Round 15
// 202.676 us; speedup vs baseline: 1.3492x; 1.0216x over previous
//
#include <hip/hip_runtime.h>

#define NEG_SLOPE 0.2f

typedef __attribute__((ext_vector_type(8))) short bf16x8;
typedef __attribute__((ext_vector_type(4))) float f32x4;

__device__ __forceinline__ unsigned short f2bf(float f) {
  unsigned u = __builtin_bit_cast(unsigned, f);
  unsigned r = u + 0x7FFFu + ((u >> 16) & 1u);   // round-to-nearest-even
  return (unsigned short)(r >> 16);
}
__device__ __forceinline__ float bflo(unsigned u) {
  return __builtin_bit_cast(float, u << 16);
}
__device__ __forceinline__ float bfhi(unsigned u) {
  return __builtin_bit_cast(float, u & 0xFFFF0000u);
}

// CSR slot: 16 B int4 = {bf16 ea01, bf16 ea23, int src, pad}

// ---------------- fused preprocessing ----------------

// blocks < eb: per-edge degree atomics + slot-ordinal precompute.
// blocks eb..eb+63: W16t transpose. block eb+64: M and vab tables.
__global__ void k_deg(const int* __restrict__ tgt, int* __restrict__ deg,
                      int* __restrict__ ord, int E, int eb,
                      const float* __restrict__ We1, const float* __restrict__ ae1,
                      const float* __restrict__ We2, const float* __restrict__ ae2,
                      const float* __restrict__ W2, const float* __restrict__ W1,
                      const float* __restrict__ as1, const float* __restrict__ ad1,
                      unsigned short* __restrict__ W16t,
                      float* __restrict__ M, float* __restrict__ vab) {
  int bid = blockIdx.x, tid = threadIdx.x;
  if (bid < eb) {
    int e = bid * 256 + tid;
    if (e < E) ord[e] = atomicAdd(&deg[tgt[e]], 1);
    return;
  }
  int mb = bid - eb;
  if (mb < 64) {
    int i = mb * 256 + tid;
    int c = i >> 7, k = i & 127;
    W16t[c * 128 + k] = f2bf(W2[k * 128 + c]);
    return;
  }
  if (tid < 64) {
    int layer = tid >> 5, kh = tid & 31;
    int k = kh >> 3, h = kh & 7;
    const float* We = layer ? We2 : We1;
    const float* ae = layer ? ae2 : ae1;
    float acc = 0.f;
    for (int c = 0; c < 16; ++c) acc += We[k * 128 + h * 16 + c] * ae[h * 16 + c];
    M[layer * 32 + k * 8 + h] = acc;
  } else if (tid < 128) {
    int i = tid - 64;
    int kind = i >> 5, rem = i & 31;
    int d = rem >> 3, h = rem & 7;
    const float* att = kind ? ad1 : as1;
    float acc = 0.f;
    for (int c = 0; c < 16; ++c) acc += W1[d * 128 + h * 16 + c] * att[h * 16 + c];
    vab[kind * 32 + d * 8 + h] = acc;
  }
}

// blocks < nbB: per-block sums of deg over 256-element chunks.
// blocks >= nbB: layer-1 node terms (a_s/a_d via low-rank vab tables).
__global__ __launch_bounds__(256) void k_bsum(const int* __restrict__ deg,
                                              int* __restrict__ bsum, int n, int nbB,
                                              const float* __restrict__ x,
                                              const float* __restrict__ vab,
                                              float* __restrict__ a_s, float* __restrict__ a_d,
                                              int N) {
  int bid = blockIdx.x, tid = threadIdx.x;
  if (bid >= nbB) {
    int idx = (bid - nbB) * 256 + tid;
    int nn = idx >> 3, h = idx & 7;
    if (nn >= N) return;
    float4 xr = *reinterpret_cast<const float4*>(x + (size_t)nn * 4);
    a_s[idx] = xr.x * vab[h] + xr.y * vab[8 + h] + xr.z * vab[16 + h] + xr.w * vab[24 + h];
    a_d[idx] = xr.x * vab[32 + h] + xr.y * vab[40 + h] + xr.z * vab[48 + h] + xr.w * vab[56 + h];
    return;
  }
  __shared__ int ws[4];
  int i = bid * 256 + tid;
  int lane = tid & 63, wv = tid >> 6;
  int v = (i < n) ? deg[i] : 0;
  #pragma unroll
  for (int o = 1; o < 64; o <<= 1) v += __shfl_xor(v, o, 64);
  if (lane == 0) ws[wv] = v;
  __syncthreads();
  if (tid == 0) bsum[bid] = ws[0] + ws[1] + ws[2] + ws[3];
}

// fused scan: each block redundantly sums bsum[0..bid), then per-block scan -> off[i+1]
__global__ __launch_bounds__(256) void k_off(const int* __restrict__ deg,
                                             const int* __restrict__ bsum,
                                             int* __restrict__ off, int n, int nbB) {
  __shared__ int ws[4];
  __shared__ int pres[4];
  int bid = blockIdx.x, tid = threadIdx.x;
  int lane = tid & 63, wv = tid >> 6;
  int partial = 0;
  for (int i = tid; i < bid; i += 256) partial += bsum[i];
  #pragma unroll
  for (int o = 1; o < 64; o <<= 1) partial += __shfl_xor(partial, o, 64);
  if (lane == 0) pres[wv] = partial;
  __syncthreads();
  int pre0 = pres[0] + pres[1] + pres[2] + pres[3];
  int i = bid * 256 + tid;
  int v = (i < n) ? deg[i] : 0;
  int sc = v;
  #pragma unroll
  for (int o = 1; o < 64; o <<= 1) { int t = __shfl_up(sc, o, 64); if (lane >= o) sc += t; }
  if (lane == 63) ws[wv] = sc;
  __syncthreads();
  int pre = pre0;
  #pragma unroll
  for (int w = 0; w < 3; ++w) if (wv > w) pre += ws[w];
  int incl = pre + sc;
  if (i < n) off[i + 1] = incl;
  if (i == 0) off[0] = 0;
}

// scatter edges into 16B CSR slots (bf16 ea + src), no atomics
__global__ void k_filledge(const int* __restrict__ src, const int* __restrict__ tgt,
                           const float* __restrict__ eattr, const int* __restrict__ ord,
                           const int* __restrict__ off, int4* __restrict__ slot, int E) {
  int e = blockIdx.x * blockDim.x + threadIdx.x;
  if (e >= E) return;
  float4 eav = reinterpret_cast<const float4*>(eattr)[e];
  int sv = src[e];
  int pos = off[tgt[e]] + ord[e];
  int4 s;
  s.x = (int)(((unsigned)f2bf(eav.y) << 16) | (unsigned)f2bf(eav.x));
  s.y = (int)(((unsigned)f2bf(eav.w) << 16) | (unsigned)f2bf(eav.z));
  s.z = sv;
  s.w = 0;
  slot[pos] = s;
}

// ---------------- layer kernels ----------------

// layer-2 linear via MFMA: h2 = x16 @ W2 (bf16 in, f32 acc). One wave per 16-node tile.
__global__ __launch_bounds__(256) void k_node2(const unsigned short* __restrict__ x16,
    const unsigned short* __restrict__ W16t,
    const float* __restrict__ as_, const float* __restrict__ ad_,
    unsigned short* __restrict__ h16, float* __restrict__ a_s, float* __restrict__ a_d, int N) {
  int wv = threadIdx.x >> 6, lane = threadIdx.x & 63;
  int n0 = (blockIdx.x * 4 + wv) * 16;
  if (n0 >= N) return;
  int r = lane & 15, g = lane >> 4;
  bf16x8 a[4];
  #pragma unroll
  for (int kb = 0; kb < 4; ++kb)
    a[kb] = *reinterpret_cast<const bf16x8*>(x16 + (size_t)(n0 + r) * 128 + kb * 32 + g * 8);
  #pragma unroll
  for (int t = 0; t < 8; ++t) {
    f32x4 acc = {0.f, 0.f, 0.f, 0.f};
    #pragma unroll
    for (int kb = 0; kb < 4; ++kb) {
      bf16x8 b = *reinterpret_cast<const bf16x8*>(W16t + (size_t)(t * 16 + r) * 128 + kb * 32 + g * 8);
      acc = __builtin_amdgcn_mfma_f32_16x16x32_bf16(a[kb], b, acc, 0, 0, 0);
    }
    float asv = as_[t * 16 + r], adv = ad_[t * 16 + r];
    float ps[4], pd[4];
    #pragma unroll
    for (int j = 0; j < 4; ++j) { ps[j] = acc[j] * asv; pd[j] = acc[j] * adv; }
    #pragma unroll
    for (int o = 1; o < 16; o <<= 1) {
      #pragma unroll
      for (int j = 0; j < 4; ++j) {
        ps[j] += __shfl_xor(ps[j], o, 64);
        pd[j] += __shfl_xor(pd[j], o, 64);
      }
    }
    #pragma unroll
    for (int j = 0; j < 4; ++j) {
      int row = n0 + g * 4 + j;
      if (row < N) {
        h16[(size_t)row * 128 + t * 16 + r] = f2bf(acc[j]);
        if (r == 0) { a_s[(size_t)row * 8 + t] = ps[j]; a_d[(size_t)row * 8 + t] = pd[j]; }
      }
    }
  }
}

// layer-1 aggregate via LINEARITY with analytic self-loop term. 16B slots.
__global__ __launch_bounds__(256) void k_aggr1(const int4* __restrict__ slot,
    const int* __restrict__ off, const float* __restrict__ a_s, const float* __restrict__ a_d,
    const float* __restrict__ M, const float* __restrict__ x,
    const float* __restrict__ W, const float* __restrict__ bias,
    unsigned short* __restrict__ x16, int N) {
  int wid = (blockIdx.x * blockDim.x + threadIdx.x) >> 6;
  if (wid >= N) return;
  int lane = threadIdx.x & 63;
  int j = lane >> 3, h = lane & 7;
  float M0 = M[h], M1 = M[8 + h], M2 = M[16 + h], M3 = M[24 + h];
  float adv = a_d[(size_t)wid * 8 + h];
  int beg = off[wid], end = off[wid + 1];
  int cnt = end - beg;
  float S = 0.f, X0 = 0.f, X1 = 0.f, X2 = 0.f, X3 = 0.f, Q = 0.f;
  for (int i = beg; i < end; i += 8) {
    int ii = i + j;
    bool act = ii < end;
    int ib = act ? ii : end - 1;
    int4 sl = slot[ib];
    int s = sl.z;
    float asv = a_s[(size_t)s * 8 + h];
    float4 xv = *reinterpret_cast<const float4*>(x + (size_t)s * 4);
    float qe = bflo(sl.x) * M0 + bfhi(sl.x) * M1 + bflo(sl.y) * M2 + bfhi(sl.y) * M3;
    float a = asv + adv + qe;
    a = a > 0.f ? a : NEG_SLOPE * a;
    float p = act ? __expf(a) : 0.f;
    Q += act ? qe : 0.f;
    S += p; X0 += p * xv.x; X1 += p * xv.y; X2 += p * xv.z; X3 += p * xv.w;
  }
  #pragma unroll
  for (int o = 8; o < 64; o <<= 1) {
    S  += __shfl_xor(S, o, 64);  Q  += __shfl_xor(Q, o, 64);
    X0 += __shfl_xor(X0, o, 64); X1 += __shfl_xor(X1, o, 64);
    X2 += __shfl_xor(X2, o, 64); X3 += __shfl_xor(X3, o, 64);
  }
  // analytic self-loop: ea_self = mean(ea) -> q_self = Q/cnt (own h class)
  {
    float qs = Q / (float)max(cnt, 1);
    float asS = a_s[(size_t)wid * 8 + h];
    float aS = asS + adv + qs;
    aS = aS > 0.f ? aS : NEG_SLOPE * aS;
    float pS = __expf(aS);
    float4 xw = *reinterpret_cast<const float4*>(x + (size_t)wid * 4);
    S += pS; X0 += pS * xw.x; X1 += pS * xw.y; X2 += pS * xw.z; X3 += pS * xw.w;
  }
  int H = lane >> 3;
  float Sh = __shfl(S, H, 64);
  float y0 = __shfl(X0, H, 64), y1 = __shfl(X1, H, 64);
  float y2 = __shfl(X2, H, 64), y3 = __shfl(X3, H, 64);
  float inv = 1.f / (Sh + 1e-16f);
  int c0 = lane * 2, c1 = lane * 2 + 1;
  float o0 = (y0 * W[c0] + y1 * W[128 + c0] + y2 * W[256 + c0] + y3 * W[384 + c0]) * inv + bias[c0];
  float o1 = (y0 * W[c1] + y1 * W[128 + c1] + y2 * W[256 + c1] + y3 * W[384 + c1]) * inv + bias[c1];
  o0 = fmaxf(o0, 0.f); o1 = fmaxf(o1, 0.f);
  unsigned pk = ((unsigned)f2bf(o1) << 16) | (unsigned)f2bf(o0);
  *reinterpret_cast<unsigned*>(x16 + (size_t)wid * 128 + lane * 2) = pk;
}

// layer-2 aggregate (single node/wave) with analytic self-loop. 16B slots, bf16 out.
__global__ __launch_bounds__(256) void k_aggr2(const int4* __restrict__ slot,
    const int* __restrict__ off, const float* __restrict__ a_s, const float* __restrict__ a_d,
    const float* __restrict__ M, const unsigned short* __restrict__ h16,
    const float* __restrict__ bias, unsigned short* __restrict__ xo16, int N) {
  int wid = (blockIdx.x * blockDim.x + threadIdx.x) >> 6;
  if (wid >= N) return;
  int lane = threadIdx.x & 63;
  int H = lane >> 3;                   // consumer head
  int ja = lane >> 3, ha = lane & 7;   // alpha role: edge ja, head ha
  float Ma0 = M[ha], Ma1 = M[8 + ha], Ma2 = M[16 + ha], Ma3 = M[24 + ha];
  float adA = a_d[(size_t)wid * 8 + ha];
  int beg = off[wid], end = off[wid + 1];
  int cnt = end - beg;
  float sum = 0.f, acc0 = 0.f, acc1 = 0.f, Q = 0.f;
  for (int i = beg; i < end; i += 8) {
    int ii = i + ja;
    bool act = ii < end;
    int ib = act ? ii : beg;
    int4 sl = slot[ib];
    int sA = sl.z;
    float asv = a_s[(size_t)sA * 8 + ha];
    float qe = bflo(sl.x) * Ma0 + bfhi(sl.x) * Ma1 + bflo(sl.y) * Ma2 + bfhi(sl.y) * Ma3;
    float a = asv + adA + qe;
    a = a > 0.f ? a : NEG_SLOPE * a;
    float p = act ? __expf(a) : 0.f;
    Q += act ? qe : 0.f;
    #pragma unroll
    for (int jj = 0; jj < 8; ++jj) {
      int sj = __shfl(sA, jj * 8, 64);
      float pj = __shfl(p, jj * 8 + H, 64);
      unsigned hu = *reinterpret_cast<const unsigned*>(h16 + (size_t)sj * 128 + lane * 2);
      sum += pj;
      acc0 += pj * bflo(hu);
      acc1 += pj * bfhi(hu);
    }
  }
  #pragma unroll
  for (int o = 8; o < 64; o <<= 1) Q += __shfl_xor(Q, o, 64);
  {
    float qs = __shfl(Q, H, 64) / (float)max(cnt, 1);
    float aS = a_s[(size_t)wid * 8 + H] + a_d[(size_t)wid * 8 + H] + qs;
    aS = aS > 0.f ? aS : NEG_SLOPE * aS;
    float pS = __expf(aS);
    unsigned hu = *reinterpret_cast<const unsigned*>(h16 + (size_t)wid * 128 + lane * 2);
    sum += pS;
    acc0 += pS * bflo(hu);
    acc1 += pS * bfhi(hu);
  }
  float inv = 1.f / (sum + 1e-16f);
  float o0 = fmaxf(acc0 * inv + bias[lane * 2], 0.f);
  float o1 = fmaxf(acc1 * inv + bias[lane * 2 + 1], 0.f);
  unsigned pk = ((unsigned)f2bf(o1) << 16) | (unsigned)f2bf(o0);
  *reinterpret_cast<unsigned*>(xo16 + (size_t)wid * 128 + lane * 2) = pk;
}

// ---------------- pooling + FC ----------------

// 64 threads: thread c handles channels (2c, 2c+1) from bf16 input
#define PROWS 128
__global__ __launch_bounds__(64) void k_pool(const unsigned short* __restrict__ xo16,
    const int* __restrict__ batch, float* __restrict__ pool, int* __restrict__ cntg, int N) {
  int c = threadIdx.x;
  int n0 = blockIdx.x * PROWS;
  if (n0 >= N) return;
  int nend = min(n0 + PROWS, N);
  float acc0 = 0.f, acc1 = 0.f; int cnt = 0; int g = batch[n0];
  for (int n = n0; n < nend; ++n) {
    int bn = batch[n];
    if (bn != g) {
      atomicAdd(&pool[(size_t)g * 128 + c * 2], acc0);
      atomicAdd(&pool[(size_t)g * 128 + c * 2 + 1], acc1);
      if (c == 0) atomicAdd(&cntg[g], cnt);
      acc0 = 0.f; acc1 = 0.f; cnt = 0; g = bn;
    }
    unsigned hu = *reinterpret_cast<const unsigned*>(xo16 + (size_t)n * 128 + c * 2);
    acc0 += bflo(hu);
    acc1 += bfhi(hu);
    cnt++;
  }
  atomicAdd(&pool[(size_t)g * 128 + c * 2], acc0);
  atomicAdd(&pool[(size_t)g * 128 + c * 2 + 1], acc1);
  if (c == 0) atomicAdd(&cntg[g], cnt);
}

__global__ __launch_bounds__(128) void k_fc(const float* __restrict__ pool,
    const int* __restrict__ cntg, const float* __restrict__ fcw,
    const float* __restrict__ fcb, float* __restrict__ out, int G) {
  int g = blockIdx.x, c = threadIdx.x;
  __shared__ float r0[2], r1[2];
  float inv = 1.f / (float)max(cntg[g], 1);
  float v = pool[(size_t)g * 128 + c] * inv;
  float p0 = v * fcw[c * 2], p1 = v * fcw[c * 2 + 1];
  for (int o = 1; o < 64; o <<= 1) { p0 += __shfl_xor(p0, o, 64); p1 += __shfl_xor(p1, o, 64); }
  if ((c & 63) == 0) { r0[c >> 6] = p0; r1[c >> 6] = p1; }
  __syncthreads();
  if (c == 0) {
    out[g * 2]     = r0[0] + r0[1] + fcb[0];
    out[g * 2 + 1] = r1[0] + r1[1] + fcb[1];
  }
}

// ---------------- host ----------------

extern "C" void kernel_launch(void* const* d_in, const int* in_sizes, int n_in,
                              void* d_out, int out_size, void* d_ws, size_t ws_size,
                              hipStream_t stream) {
  const float* x     = (const float*)d_in[0];
  const int*   eidx  = (const int*)d_in[1];
  const int*   batch = (const int*)d_in[2];
  const float* eattr = (const float*)d_in[3];
  const float* W1  = (const float*)d_in[4];
  const float* as1 = (const float*)d_in[5];
  const float* ad1 = (const float*)d_in[6];
  const float* We1 = (const float*)d_in[7];
  const float* ae1 = (const float*)d_in[8];
  const float* b1  = (const float*)d_in[9];
  const float* W2  = (const float*)d_in[10];
  const float* as2 = (const float*)d_in[11];
  const float* ad2 = (const float*)d_in[12];
  const float* We2 = (const float*)d_in[13];
  const float* ae2 = (const float*)d_in[14];
  const float* b2  = (const float*)d_in[15];
  const float* fcw = (const float*)d_in[16];
  const float* fcb = (const float*)d_in[17];

  const int N  = in_sizes[2];
  const int E  = in_sizes[1] / 2;
  const int G  = out_size / 2;
  const int eb = (E + 255) / 256;
  const int nbB = (N + 255) / 256;
  const int n1b = (N * 8 + 255) / 256;
  const int* srcI = eidx;
  const int* tgtI = eidx + E;

  char* w = (char*)d_ws;
  auto alloc = [&](size_t bytes) -> void* {
    void* p = (void*)w;
    w += (bytes + 255) & ~(size_t)255;
    return p;
  };
  int*   deg    = (int*)alloc((size_t)N * 4);
  int*   ord    = (int*)alloc((size_t)E * 4);
  int*   bsum   = (int*)alloc((size_t)nbB * 4);
  int*   off    = (int*)alloc((size_t)(N + 1) * 4);
  int4*  slot   = (int4*)alloc((size_t)E * 16);
  float* a_s    = (float*)alloc((size_t)N * 32);
  float* a_d    = (float*)alloc((size_t)N * 32);
  unsigned short* x16  = (unsigned short*)alloc((size_t)N * 256);
  unsigned short* h16  = (unsigned short*)alloc((size_t)N * 256);
  unsigned short* xo16 = (unsigned short*)alloc((size_t)N * 256);
  unsigned short* W16t = (unsigned short*)alloc(128 * 128 * 2);
  float* M      = (float*)alloc(512);                // M[64] + vab[64]
  float* vab    = M + 64;
  float* pool   = (float*)alloc((size_t)G * 512 + (size_t)G * 4);
  int*   cntg   = (int*)(pool + (size_t)G * 128);

  hipMemsetAsync(deg, 0, (size_t)N * 4, stream);
  hipMemsetAsync(pool, 0, (size_t)G * 516, stream);

  k_deg<<<eb + 65, 256, 0, stream>>>(tgtI, deg, ord, E, eb,
                                     We1, ae1, We2, ae2, W2, W1, as1, ad1, W16t, M, vab);
  k_bsum<<<nbB + n1b, 256, 0, stream>>>(deg, bsum, N, nbB, x, vab, a_s, a_d, N);
  k_off<<<nbB, 256, 0, stream>>>(deg, bsum, off, N, nbB);
  k_filledge<<<eb, 256, 0, stream>>>(srcI, tgtI, eattr, ord, off, slot, E);

  // layer 1 (linearity + analytic self-loop); output packed bf16
  k_aggr1<<<(N + 3) / 4, 256, 0, stream>>>(slot, off, a_s, a_d, M, x, W1, b1, x16, N);

  // layer 2 (MFMA linear + gather aggregate with analytic self-loop)
  k_node2<<<(N + 63) / 64, 256, 0, stream>>>(x16, W16t, as2, ad2, h16, a_s, a_d, N);
  k_aggr2<<<(N + 3) / 4, 256, 0, stream>>>(slot, off, a_s, a_d, M + 32, h16, b2, xo16, N);

  // pool + fc
  k_pool<<<(N + PROWS - 1) / PROWS, 64, 0, stream>>>(xo16, batch, pool, cntg, N);
  k_fc<<<G, 128, 0, stream>>>(pool, cntg, fcw, fcb, (float*)d_out, G);
}